// Round 12
// baseline (672.074 us; speedup 1.0000x reference)
//
#include <hip/hip_runtime.h>
#include <hip/hip_bf16.h>
#include <cstdint>
#include <cstddef>

// DecoderBlock: B=2, T=2048, D=1024, H=16, HD=64, MLP=4096. M = B*T = 4096 tokens.
// fp32 I/O, bf16 MFMA internals (threshold is 2% of absmax -> bf16-safe).

#define DEV __device__ __forceinline__

typedef short bf16x8 __attribute__((ext_vector_type(8)));
typedef float f32x4  __attribute__((ext_vector_type(4)));

// softmax scale folded into Q-projection weights: 1/sqrt(64) * log2(e)
#define QSCALE 0.18033688011112042f

DEV unsigned short f2bf(float f) {                 // RNE f32 -> bf16
  unsigned int u = __builtin_bit_cast(unsigned int, f);
  u = u + 0x7FFFu + ((u >> 16) & 1u);
  return (unsigned short)(u >> 16);
}

DEV unsigned int cvt_pk_bf16(float lo, float hi) { // 2xf32 -> packed 2xbf16 (RNE)
  unsigned int r;
  asm volatile("v_cvt_pk_bf16_f32 %0, %1, %2" : "=v"(r) : "v"(lo), "v"(hi));
  return r;
}

DEV void gload_lds16(const void* g, void* lds) {   // 16B direct global->LDS
  __builtin_amdgcn_global_load_lds(
      (const __attribute__((address_space(1))) void*)g,
      (__attribute__((address_space(3))) void*)lds, 16, 0, 0);
}

// ---------------- weight transpose fp32[K][N] -> bf16[N][K], cols [s0,s1) scaled ----------------
__global__ __launch_bounds__(256) void k_transpose_bf16(
    const float* __restrict__ in, unsigned short* __restrict__ out, int K, int N,
    int s0, int s1, float sc) {
  __shared__ float tile[32][33];
  const int n0 = blockIdx.x * 32, k0 = blockIdx.y * 32;
  const int tx = threadIdx.x, ty = threadIdx.y;   // block (32,8)
#pragma unroll
  for (int i = 0; i < 32; i += 8)
    tile[ty + i][tx] = in[(size_t)(k0 + ty + i) * N + n0 + tx];
  __syncthreads();
#pragma unroll
  for (int i = 0; i < 32; i += 8) {
    const int n = n0 + ty + i;
    float v = tile[tx][ty + i];
    if (n >= s0 && n < s1) v *= sc;
    out[(size_t)n * K + k0 + tx] = f2bf(v);
  }
}

// ---------------- bias copy with region scaling ----------------
__global__ __launch_bounds__(256) void k_scale_bias(
    const float* __restrict__ in, float* __restrict__ out, int n, int s0, int s1, float sc) {
  const int i = blockIdx.x * 256 + threadIdx.x;
  if (i < n) out[i] = in[i] * ((i >= s0 && i < s1) ? sc : 1.0f);
}

// ---------------- bf16 strided V[k][d] -> vt[bh][d][k] transpose ----------------
__global__ __launch_bounds__(256) void k_vtrans(
    const unsigned short* __restrict__ V, int ldv, int vo0,
    unsigned short* __restrict__ vt, int TK) {
  __shared__ unsigned short tile[32][33];
  const int k0 = blockIdx.x * 32;
  const int d0 = (blockIdx.y & 1) * 32;
  const int bh = blockIdx.z;                      // b*H + h
  const int b = bh >> 4, h = bh & 15;
  const int tx = threadIdx.x, ty = threadIdx.y;   // block (32,8)
  const size_t tok0 = (size_t)b * 2048;
#pragma unroll
  for (int i = 0; i < 32; i += 8)
    tile[ty + i][tx] = V[(tok0 + k0 + ty + i) * ldv + vo0 + h * 64 + d0 + tx];
  __syncthreads();
#pragma unroll
  for (int i = 0; i < 32; i += 8)
    vt[((size_t)bh * 64 + d0 + ty + i) * TK + k0 + tx] = tile[tx][ty + i];
}

// ---------------- fp32 -> bf16 elementwise (x4 vectorized) ----------------
__global__ __launch_bounds__(256) void k_f32_to_bf16(
    const float* __restrict__ in, unsigned short* __restrict__ out, int n4) {
  const int i = blockIdx.x * 256 + threadIdx.x;
  if (i < n4) {
    const float4 v = ((const float4*)in)[i];
    ushort4 o;
    o.x = f2bf(v.x); o.y = f2bf(v.y); o.z = f2bf(v.z); o.w = f2bf(v.w);
    ((ushort4*)out)[i] = o;
  }
}

// ---------------- LayerNorm fp32 -> bf16 (one row / block, D=1024) ----------------
__global__ __launch_bounds__(256) void k_ln(
    const float* __restrict__ x, const float* __restrict__ g,
    const float* __restrict__ bt, unsigned short* __restrict__ y) {
  const int row = blockIdx.x, t = threadIdx.x;
  const float4 v = ((const float4*)(x + (size_t)row * 1024))[t];
  float s1 = v.x + v.y + v.z + v.w;
  float s2 = v.x * v.x + v.y * v.y + v.z * v.z + v.w * v.w;
#pragma unroll
  for (int off = 1; off < 64; off <<= 1) {
    s1 += __shfl_xor(s1, off);
    s2 += __shfl_xor(s2, off);
  }
  __shared__ float r1[4], r2[4];
  if ((t & 63) == 0) { r1[t >> 6] = s1; r2[t >> 6] = s2; }
  __syncthreads();
  const float tot1 = r1[0] + r1[1] + r1[2] + r1[3];
  const float tot2 = r2[0] + r2[1] + r2[2] + r2[3];
  const float mean = tot1 * (1.0f / 1024.0f);
  const float var  = tot2 * (1.0f / 1024.0f) - mean * mean;
  const float rstd = rsqrtf(var + 1e-5f);
  const float4 gg = ((const float4*)g)[t];
  const float4 bb = ((const float4*)bt)[t];
  ushort4 o;
  o.x = f2bf((v.x - mean) * rstd * gg.x + bb.x);
  o.y = f2bf((v.y - mean) * rstd * gg.y + bb.y);
  o.z = f2bf((v.z - mean) * rstd * gg.z + bb.z);
  o.w = f2bf((v.w - mean) * rstd * gg.w + bb.w);
  ((ushort4*)(y + (size_t)row * 1024))[t] = o;
}

// ---------------- GEMM: C[M][N] = A[M][K](bf16) * Bt[N][K]^T(bf16) + bias ----------------
// EPI 0: store bf16. EPI 1: += resid (fp32), store fp32. EPI 2: exact GELU, store bf16.
// BN=128: 128x128 tile. BN=64: 128x64 tile for N=1024 GEMMs (2 blocks/CU).
// XCD-aware chunked block swizzle (T1): all grids have nwg%8==0 -> bijective.
template <int EPI, int BN>
__global__ __launch_bounds__(256) void k_gemm(
    const unsigned short* __restrict__ A, const unsigned short* __restrict__ Bt,
    const float* __restrict__ bias, const float* __restrict__ resid,
    unsigned short* __restrict__ Obf, float* __restrict__ Of, int N, int K) {
  constexpr int NFR = BN / 32;                    // n-frags per wave: 4 or 2
  __shared__ __align__(16) unsigned short As[128 * 32];
  __shared__ __align__(16) unsigned short Bs[BN * 32];
  const int tid = threadIdx.x;
  const int wave = tid >> 6, lane = tid & 63;
  const int nwg = gridDim.x * gridDim.y;
  const int wg = blockIdx.y * gridDim.x + blockIdx.x;
  const int swz = (wg & 7) * (nwg >> 3) + (wg >> 3);   // chunked XCD swizzle
  const int bn = swz % gridDim.x, bm = swz / gridDim.x;
  const int la = lane & 15, ks = (lane >> 4) * 8;
  const int wr = wave >> 1, wc = wave & 1;
  f32x4 acc[4][NFR] = {};
  const int rsub = lane >> 2;                     // 0..15: row within 16-row chunk
  const int kk = (lane & 3) * 8;
  const unsigned short* ga = A  + (size_t)(bm * 128 + wave * 32 + rsub) * K + kk;
  const unsigned short* gb = Bt + (size_t)(bn * BN + wave * (BN / 4) + rsub) * K + kk;
  unsigned short* lA0 = &As[(wave * 32) * 32];
  unsigned short* lA1 = &As[(wave * 32 + 16) * 32];
  unsigned short* lB0 = &Bs[(wave * (BN / 4)) * 32];
  unsigned short* lB1 = &Bs[(wave * (BN / 4) + 16) * 32];
  for (int kt = 0; kt < K; kt += 32) {
    gload_lds16(ga + kt,                  lA0);
    gload_lds16(ga + kt + (size_t)16 * K, lA1);
    gload_lds16(gb + kt,                  lB0);
    if constexpr (BN == 128) gload_lds16(gb + kt + (size_t)16 * K, lB1);
    __syncthreads();
    bf16x8 af[4], bfr[NFR];
#pragma unroll
    for (int m = 0; m < 4; ++m)
      af[m] = *(const bf16x8*)&As[(wr * 64 + m * 16 + la) * 32 + ks];
#pragma unroll
    for (int n = 0; n < NFR; ++n)
      bfr[n] = *(const bf16x8*)&Bs[(wc * (BN / 2) + n * 16 + la) * 32 + ks];
#pragma unroll
    for (int m = 0; m < 4; ++m)
#pragma unroll
      for (int n = 0; n < NFR; ++n)
        acc[m][n] = __builtin_amdgcn_mfma_f32_16x16x32_bf16(af[m], bfr[n], acc[m][n], 0, 0, 0);
    __syncthreads();
  }
#pragma unroll
  for (int m = 0; m < 4; ++m) {
    const int row = bm * 128 + wr * 64 + m * 16 + (lane >> 4) * 4;
#pragma unroll
    for (int n = 0; n < NFR; ++n) {
      const int col = bn * BN + wc * (BN / 2) + n * 16 + la;
      const float bv = bias[col];
#pragma unroll
      for (int r = 0; r < 4; ++r) {
        float v = acc[m][n][r] + bv;
        const size_t idx = (size_t)(row + r) * N + col;
        if constexpr (EPI == 0) {
          Obf[idx] = f2bf(v);
        } else if constexpr (EPI == 1) {
          Of[idx] = v + resid[idx];
        } else {
          v = 0.5f * v * (1.0f + erff(v * 0.70710678118654752f));
          Obf[idx] = f2bf(v);
        }
      }
    }
  }
}

// ---------------- flash attention v5 ----------------
// Software-pipelined (T15): per iter, issue QK^T(t) MFMAs, then run
// softmax(t-1)+PV(t-1) on the VALU while they execute. V triple-buffered,
// K double-buffered -> ONE raw barrier per iteration; stage(t+1) issued at
// iter top and waited (vmcnt 0) at next top. Scale pre-folded (exp2 domain),
// cvt_pk bf16 pack, defer-rescale. Causal mask only in the epilogue call.
template <bool CAUSAL>
__global__ __launch_bounds__(256) void k_attn5(
    const unsigned short* __restrict__ Qb, int ldq, int qo0,
    const unsigned short* __restrict__ Kb, int ldk, int ko0,
    const unsigned short* __restrict__ Vtg,        // [b*H+h][64][TK]
    unsigned short* __restrict__ O, int TK) {
  __shared__ __align__(16) unsigned short Ks[2][64 * 64];
  __shared__ __align__(16) unsigned short Vs[3][64 * 64];
  __shared__ __align__(16) unsigned short Pl[4][16 * 64];
  const int qt = (blockIdx.x + blockIdx.y) & 31;   // balance causal work per CU
  const int h = blockIdx.y, b = blockIdx.z;
  const int bh = b * 16 + h;
  const int tid = threadIdx.x, wave = tid >> 6, lane = tid & 63;
  const int la = lane & 15, g = lane >> 4;
  const int qoff = qo0 + h * 64, koff = ko0 + h * 64;
  const size_t tok0 = (size_t)b * 2048;

  bf16x8 qf[2];                                    // Q as B-frag: col q=la, k=hd
  {
    const unsigned short* qp =
        Qb + (tok0 + qt * 64 + wave * 16 + la) * ldq + qoff + g * 8;
    qf[0] = *(const bf16x8*)qp;
    qf[1] = *(const bf16x8*)(qp + 32);
  }
  f32x4 oacc[4] = {};                              // O^T: col q=la, row d=g*4+r (+16*n4)
  f32x4 sp[4];                                     // S(t-1), consumed one iter late
  float m_r = -1e30f, l_r = 0.0f;
  const int nkt = CAUSAL ? (qt + 1) : (TK >> 6);

  // staging: 64 rows x 128B per tile; wave w round r covers rows w*8+r*32..+8.
  const int rr = lane >> 3, cc = lane & 7;
  const int sc = (cc ^ rr) * 8;                    // pre-swizzled source chunk
  const unsigned short* Vrow = Vtg + (size_t)bh * 64 * TK;
  auto stage = [&](int kt, unsigned short* kb, unsigned short* vb) {
#pragma unroll
    for (int r = 0; r < 2; ++r) {
      const int row = wave * 8 + r * 32 + rr;
      gload_lds16(Kb + (tok0 + kt * 64 + row) * ldk + koff + sc,
                  kb + (wave * 8 + r * 32) * 64);
      gload_lds16(Vrow + (size_t)row * TK + kt * 64 + sc,
                  vb + (wave * 8 + r * 32) * 64);
    }
  };

  char* pw = (char*)Pl[wave];
  const int lsw = (la & 7) << 4;

  // softmax + PV for the tile whose S is in sp[] and whose V is at vbB
  auto sm_pv = [&](const char* vbB, bool domask) {
    if (CAUSAL && domask) {
      const int qloc = wave * 16 + la;
#pragma unroll
      for (int n = 0; n < 4; ++n)
#pragma unroll
        for (int r = 0; r < 4; ++r)
          if (n * 16 + g * 4 + r > qloc) sp[n][r] = -1e30f;
    }
    float t0 = fmaxf(fmaxf(sp[0][0], sp[0][1]), fmaxf(sp[0][2], sp[0][3]));
    float t1 = fmaxf(fmaxf(sp[1][0], sp[1][1]), fmaxf(sp[1][2], sp[1][3]));
    float t2 = fmaxf(fmaxf(sp[2][0], sp[2][1]), fmaxf(sp[2][2], sp[2][3]));
    float t3 = fmaxf(fmaxf(sp[3][0], sp[3][1]), fmaxf(sp[3][2], sp[3][3]));
    float tm = fmaxf(fmaxf(t0, t1), fmaxf(t2, t3));
    tm = fmaxf(tm, __shfl_xor(tm, 16, 64));        // reduce across g (keeps la=q)
    tm = fmaxf(tm, __shfl_xor(tm, 32, 64));
    if (!__all(tm <= m_r + 8.0f)) {                // T13: rescale only on real growth
      const float mn = fmaxf(m_r, tm);
      const float al = exp2f(m_r - mn);
      m_r = mn;
      l_r *= al;
#pragma unroll
      for (int n4 = 0; n4 < 4; ++n4)
#pragma unroll
        for (int r = 0; r < 4; ++r) oacc[n4][r] *= al;
    }
    float p[4][4];
#pragma unroll
    for (int n = 0; n < 4; ++n)
#pragma unroll
      for (int r = 0; r < 4; ++r) p[n][r] = exp2f(sp[n][r] - m_r);  // bounded by 2^8
    float rs = ((p[0][0] + p[0][1]) + (p[0][2] + p[0][3]))
             + ((p[1][0] + p[1][1]) + (p[1][2] + p[1][3]))
             + ((p[2][0] + p[2][1]) + (p[2][2] + p[2][3]))
             + ((p[3][0] + p[3][1]) + (p[3][2] + p[3][3]));
    rs += __shfl_xor(rs, 16, 64);
    rs += __shfl_xor(rs, 32, 64);
    l_r += rs;
    // P^T -> per-wave LDS row q=la (cvt_pk u32 writes, swizzled)
#pragma unroll
    for (int n = 0; n < 4; ++n)
#pragma unroll
      for (int rp = 0; rp < 2; ++rp) {
        const unsigned int w = cvt_pk_bf16(p[n][2 * rp], p[n][2 * rp + 1]);
        *(unsigned int*)(pw + la * 128 + ((n * 32 + g * 8 + rp * 4) ^ lsw)) = w;
      }
    asm volatile("s_waitcnt lgkmcnt(0)" ::: "memory");
    const bf16x8 pb0 = *(const bf16x8*)(pw + la * 128 + ((g * 16) ^ lsw));
    const bf16x8 pb1 = *(const bf16x8*)(pw + la * 128 + ((64 + g * 16) ^ lsw));
    // O^T += V^T P^T
    __builtin_amdgcn_s_setprio(1);
#pragma unroll
    for (int kc = 0; kc < 2; ++kc)
#pragma unroll
      for (int n4 = 0; n4 < 4; ++n4) {
        const int d = n4 * 16 + la;
        const bf16x8 vfrag = *(const bf16x8*)(vbB +
            d * 128 + ((kc * 64 + g * 16) ^ ((d & 7) << 4)));
        oacc[n4] = __builtin_amdgcn_mfma_f32_16x16x32_bf16(
            vfrag, kc ? pb1 : pb0, oacc[n4], 0, 0, 0);
      }
    __builtin_amdgcn_s_setprio(0);
  };

  unsigned short* vbP = Vs[2];                     // V(t-1)
  unsigned short* vbC = Vs[0];                     // V(t)
  unsigned short* vbN = Vs[1];                     // V(t+1) landing zone
  stage(0, Ks[0], vbC);
  int kcur = 0;

  for (int t = 0; t < nkt; ++t) {
    asm volatile("s_waitcnt vmcnt(0)" ::: "memory");  // own stage(t) landed
    __builtin_amdgcn_s_barrier();                     // all waves' stage(t) landed
    if (t + 1 < nkt) stage(t + 1, Ks[kcur ^ 1], vbN);

    // ---- issue QK^T(t): 8 MFMA from Ks[kcur]; VALU below overlaps ----
    f32x4 sn[4] = {};
    __builtin_amdgcn_s_setprio(1);
#pragma unroll
    for (int kc = 0; kc < 2; ++kc)
#pragma unroll
      for (int n = 0; n < 4; ++n) {
        const int key = n * 16 + la;
        const bf16x8 kfr = *(const bf16x8*)((const char*)Ks[kcur] +
            key * 128 + ((kc * 64 + g * 16) ^ ((key & 7) << 4)));
        sn[n] = __builtin_amdgcn_mfma_f32_16x16x32_bf16(kfr, qf[kc], sn[n], 0, 0, 0);
      }
    __builtin_amdgcn_s_setprio(0);

    if (t > 0) sm_pv((const char*)vbP, false);     // softmax+PV of tile t-1

    sp[0] = sn[0]; sp[1] = sn[1]; sp[2] = sn[2]; sp[3] = sn[3];
    unsigned short* tmp = vbP; vbP = vbC; vbC = vbN; vbN = tmp;
    kcur ^= 1;
  }
  sm_pv((const char*)vbP, true);                   // last tile (mask here if causal)

  // ---- epilogue: O^T -> LDS transpose -> coalesced O[q][d] stores ----
  asm volatile("s_waitcnt lgkmcnt(0)" ::: "memory");
  const float inv = 1.0f / l_r;
#pragma unroll
  for (int n4 = 0; n4 < 4; ++n4)
#pragma unroll
    for (int rp = 0; rp < 2; ++rp) {
      const unsigned int w = cvt_pk_bf16(oacc[n4][2 * rp] * inv, oacc[n4][2 * rp + 1] * inv);
      *(unsigned int*)(pw + la * 128 + ((n4 * 32 + g * 8 + rp * 4) ^ lsw)) = w;
    }
  asm volatile("s_waitcnt lgkmcnt(0)" ::: "memory");
  const int q2 = lane >> 2, c4 = lane & 3;
  const size_t orow = tok0 + qt * 64 + wave * 16 + q2;
#pragma unroll
  for (int h8 = 0; h8 < 2; ++h8) {
    const bf16x8 v = *(const bf16x8*)(pw + q2 * 128 +
        ((c4 * 32 + h8 * 16) ^ ((q2 & 7) << 4)));
    *(bf16x8*)&O[orow * 1024 + h * 64 + c4 * 16 + h8 * 8] = v;
  }
}

// ---------------- workspace layout ----------------
constexpr size_t SZ_1K1K  = 1024ull * 1024 * 2;
constexpr size_t OFF_WQKV = 0;                         constexpr size_t SZ_WQKV = 3072ull * 1024 * 2;
constexpr size_t OFF_WPRJ = OFF_WQKV + SZ_WQKV;
constexpr size_t OFF_WQ   = OFF_WPRJ + SZ_1K1K;
constexpr size_t OFF_WKV  = OFF_WQ + SZ_1K1K;          constexpr size_t SZ_WKV = 2048ull * 1024 * 2;
constexpr size_t OFF_WCO  = OFF_WKV + SZ_WKV;
constexpr size_t OFF_WM1  = OFF_WCO + SZ_1K1K;         constexpr size_t SZ_WM1 = 4096ull * 1024 * 2;
constexpr size_t OFF_WM2  = OFF_WM1 + SZ_WM1;          constexpr size_t SZ_WM2 = 1024ull * 4096 * 2;
constexpr size_t OFF_ENCB = OFF_WM2 + SZ_WM2;          constexpr size_t SZ_ACT = 4096ull * 1024 * 2;
constexpr size_t OFF_XCUR = OFF_ENCB + SZ_ACT;         constexpr size_t SZ_XF  = 4096ull * 1024 * 4;
constexpr size_t OFF_LNO  = OFF_XCUR + SZ_XF;
constexpr size_t OFF_BIG  = OFF_LNO + SZ_ACT;          constexpr size_t SZ_BIG = 4096ull * 4096 * 2;
constexpr size_t OFF_ATTN = OFF_BIG + SZ_BIG;
constexpr size_t OFF_QPRJ = OFF_ATTN + SZ_ACT;
constexpr size_t OFF_BQKV = OFF_QPRJ + SZ_ACT;         // scaled qkv bias (3072 f32)
constexpr size_t OFF_BQ   = OFF_BQKV + 3072 * 4;       // scaled q bias (1024 f32)
constexpr size_t WS_NEED  = OFF_BQ + 1024 * 4;

extern "C" void kernel_launch(void* const* d_in, const int* in_sizes, int n_in,
                              void* d_out, int out_size, void* d_ws, size_t ws_size,
                              hipStream_t stream) {
  (void)in_sizes; (void)n_in; (void)out_size;
  if (ws_size < WS_NEED) return;  // workspace too small -> visible as absmax fail

  const float* x     = (const float*)d_in[0];
  const float* enc   = (const float*)d_in[1];
  const float* ln1g  = (const float*)d_in[3];
  const float* ln1b  = (const float*)d_in[4];
  const float* ln2g  = (const float*)d_in[5];
  const float* ln2b  = (const float*)d_in[6];
  const float* ln3g  = (const float*)d_in[7];
  const float* ln3b  = (const float*)d_in[8];
  const float* qkv_w = (const float*)d_in[9];
  const float* qkv_b = (const float*)d_in[10];
  const float* prj_w = (const float*)d_in[11];
  const float* prj_b = (const float*)d_in[12];
  const float* q_w   = (const float*)d_in[13];
  const float* q_b   = (const float*)d_in[14];
  const float* kv_w  = (const float*)d_in[15];
  const float* kv_b  = (const float*)d_in[16];
  const float* co_w  = (const float*)d_in[17];
  const float* co_b  = (const float*)d_in[18];
  const float* m1_w  = (const float*)d_in[19];
  const float* m1_b  = (const float*)d_in[20];
  const float* m2_w  = (const float*)d_in[21];
  const float* m2_b  = (const float*)d_in[22];
  float* out = (float*)d_out;

  char* ws = (char*)d_ws;
  unsigned short* wqkv = (unsigned short*)(ws + OFF_WQKV);
  unsigned short* wprj = (unsigned short*)(ws + OFF_WPRJ);
  unsigned short* wq   = (unsigned short*)(ws + OFF_WQ);
  unsigned short* wkv  = (unsigned short*)(ws + OFF_WKV);
  unsigned short* wco  = (unsigned short*)(ws + OFF_WCO);
  unsigned short* wm1  = (unsigned short*)(ws + OFF_WM1);
  unsigned short* wm2  = (unsigned short*)(ws + OFF_WM2);
  unsigned short* encb = (unsigned short*)(ws + OFF_ENCB);
  float*          xcur = (float*)(ws + OFF_XCUR);
  unsigned short* lno  = (unsigned short*)(ws + OFF_LNO);
  unsigned short* big  = (unsigned short*)(ws + OFF_BIG);
  unsigned short* attnb= (unsigned short*)(ws + OFF_ATTN);
  unsigned short* qprj = (unsigned short*)(ws + OFF_QPRJ);
  float*          bqkv = (float*)(ws + OFF_BQKV);
  float*          bq   = (float*)(ws + OFF_BQ);
  // V^T scratch lives in the unused tail of `big`:
  unsigned short* vtS  = big + (size_t)4096 * 3072;
  unsigned short* vtC  = big + (size_t)4096 * 2048;

  const dim3 tb(32, 8);
  // weights -> bf16 transposed [N][K]; Q-producing columns pre-scaled by QSCALE
  k_transpose_bf16<<<dim3(3072/32, 1024/32), tb, 0, stream>>>(qkv_w, wqkv, 1024, 3072, 0, 1024, QSCALE);
  k_transpose_bf16<<<dim3(1024/32, 1024/32), tb, 0, stream>>>(prj_w, wprj, 1024, 1024, 0, 0, 1.0f);
  k_transpose_bf16<<<dim3(1024/32, 1024/32), tb, 0, stream>>>(q_w,   wq,   1024, 1024, 0, 1024, QSCALE);
  k_transpose_bf16<<<dim3(2048/32, 1024/32), tb, 0, stream>>>(kv_w,  wkv,  1024, 2048, 0, 0, 1.0f);
  k_transpose_bf16<<<dim3(1024/32, 1024/32), tb, 0, stream>>>(co_w,  wco,  1024, 1024, 0, 0, 1.0f);
  k_transpose_bf16<<<dim3(4096/32, 1024/32), tb, 0, stream>>>(m1_w,  wm1,  1024, 4096, 0, 0, 1.0f);
  k_transpose_bf16<<<dim3(1024/32, 4096/32), tb, 0, stream>>>(m2_w,  wm2,  4096, 1024, 0, 0, 1.0f);
  k_scale_bias<<<12, 256, 0, stream>>>(qkv_b, bqkv, 3072, 0, 1024, QSCALE);
  k_scale_bias<<<4, 256, 0, stream>>>(q_b, bq, 1024, 0, 1024, QSCALE);
  k_f32_to_bf16<<<4096, 256, 0, stream>>>(enc, encb, 1048576);

  // ---- self-attention block ----
  k_ln<<<4096, 256, 0, stream>>>(x, ln1g, ln1b, lno);
  k_gemm<0,128><<<dim3(24, 32), 256, 0, stream>>>(lno, wqkv, bqkv, nullptr, big, nullptr, 3072, 1024);
  k_vtrans<<<dim3(64, 2, 32), tb, 0, stream>>>(big, 3072, 2048, vtS, 2048);
  k_attn5<true><<<dim3(32, 16, 2), 256, 0, stream>>>(big, 3072, 0,
                                                     big, 3072, 1024,
                                                     vtS, attnb, 2048);
  k_gemm<1,64><<<dim3(16, 32), 256, 0, stream>>>(attnb, wprj, prj_b, x, nullptr, xcur, 1024, 1024);

  // ---- cross-attention block ----
  k_ln<<<4096, 256, 0, stream>>>(xcur, ln2g, ln2b, lno);
  k_gemm<0,64><<<dim3(16, 32), 256, 0, stream>>>(lno,  wq,  bq,   nullptr, qprj, nullptr, 1024, 1024);
  k_gemm<0,128><<<dim3(16, 32), 256, 0, stream>>>(encb, wkv, kv_b, nullptr, big,  nullptr, 2048, 1024);
  k_vtrans<<<dim3(64, 2, 32), tb, 0, stream>>>(big, 2048, 1024, vtC, 2048);
  k_attn5<false><<<dim3(32, 16, 2), 256, 0, stream>>>(qprj, 1024, 0,
                                                      big,  2048, 0,
                                                      vtC, attnb, 2048);
  k_gemm<1,64><<<dim3(16, 32), 256, 0, stream>>>(attnb, wco, co_b, xcur, nullptr, xcur, 1024, 1024);

  // ---- MLP block ----
  k_ln<<<4096, 256, 0, stream>>>(xcur, ln3g, ln3b, lno);
  k_gemm<2,128><<<dim3(32, 32), 256, 0, stream>>>(lno, wm1, m1_b, nullptr, big, nullptr, 4096, 1024);
  k_gemm<1,64><<<dim3(16, 32), 256, 0, stream>>>(big, wm2, m2_b, xcur, nullptr, out, 1024, 4096);
}

// Round 14
// 626.935 us; speedup vs baseline: 1.0720x; 1.0720x over previous
//
#include <hip/hip_runtime.h>
#include <hip/hip_bf16.h>
#include <cstdint>
#include <cstddef>

// DecoderBlock: B=2, T=2048, D=1024, H=16, HD=64, MLP=4096. M = B*T = 4096 tokens.
// fp32 I/O, bf16 MFMA internals (threshold is 2% of absmax -> bf16-safe).

#define DEV __device__ __forceinline__

typedef short bf16x8 __attribute__((ext_vector_type(8)));
typedef float f32x4  __attribute__((ext_vector_type(4)));

// softmax scale folded into Q-projection weights: 1/sqrt(64) * log2(e)
#define QSCALE 0.18033688011112042f

DEV unsigned short f2bf(float f) {                 // RNE f32 -> bf16
  unsigned int u = __builtin_bit_cast(unsigned int, f);
  u = u + 0x7FFFu + ((u >> 16) & 1u);
  return (unsigned short)(u >> 16);
}

DEV unsigned int cvt_pk_bf16(float lo, float hi) { // 2xf32 -> packed 2xbf16 (RNE)
  unsigned int r;
  asm volatile("v_cvt_pk_bf16_f32 %0, %1, %2" : "=v"(r) : "v"(lo), "v"(hi));
  return r;
}

DEV void gload_lds16(const void* g, void* lds) {   // 16B direct global->LDS
  __builtin_amdgcn_global_load_lds(
      (const __attribute__((address_space(1))) void*)g,
      (__attribute__((address_space(3))) void*)lds, 16, 0, 0);
}

// ---------------- weight transpose fp32[K][N] -> bf16[N][K], cols [s0,s1) scaled ----------------
__global__ __launch_bounds__(256) void k_transpose_bf16(
    const float* __restrict__ in, unsigned short* __restrict__ out, int K, int N,
    int s0, int s1, float sc) {
  __shared__ float tile[32][33];
  const int n0 = blockIdx.x * 32, k0 = blockIdx.y * 32;
  const int tx = threadIdx.x, ty = threadIdx.y;   // block (32,8)
#pragma unroll
  for (int i = 0; i < 32; i += 8)
    tile[ty + i][tx] = in[(size_t)(k0 + ty + i) * N + n0 + tx];
  __syncthreads();
#pragma unroll
  for (int i = 0; i < 32; i += 8) {
    const int n = n0 + ty + i;
    float v = tile[tx][ty + i];
    if (n >= s0 && n < s1) v *= sc;
    out[(size_t)n * K + k0 + tx] = f2bf(v);
  }
}

// ---------------- bias copy with region scaling ----------------
__global__ __launch_bounds__(256) void k_scale_bias(
    const float* __restrict__ in, float* __restrict__ out, int n, int s0, int s1, float sc) {
  const int i = blockIdx.x * 256 + threadIdx.x;
  if (i < n) out[i] = in[i] * ((i >= s0 && i < s1) ? sc : 1.0f);
}

// ---------------- bf16 strided V[k][d] -> vt[bh][d][k] transpose ----------------
__global__ __launch_bounds__(256) void k_vtrans(
    const unsigned short* __restrict__ V, int ldv, int vo0,
    unsigned short* __restrict__ vt, int TK) {
  __shared__ unsigned short tile[32][33];
  const int k0 = blockIdx.x * 32;
  const int d0 = (blockIdx.y & 1) * 32;
  const int bh = blockIdx.z;                      // b*H + h
  const int b = bh >> 4, h = bh & 15;
  const int tx = threadIdx.x, ty = threadIdx.y;   // block (32,8)
  const size_t tok0 = (size_t)b * 2048;
#pragma unroll
  for (int i = 0; i < 32; i += 8)
    tile[ty + i][tx] = V[(tok0 + k0 + ty + i) * ldv + vo0 + h * 64 + d0 + tx];
  __syncthreads();
#pragma unroll
  for (int i = 0; i < 32; i += 8)
    vt[((size_t)bh * 64 + d0 + ty + i) * TK + k0 + tx] = tile[tx][ty + i];
}

// ---------------- fp32 -> bf16 elementwise (x4 vectorized) ----------------
__global__ __launch_bounds__(256) void k_f32_to_bf16(
    const float* __restrict__ in, unsigned short* __restrict__ out, int n4) {
  const int i = blockIdx.x * 256 + threadIdx.x;
  if (i < n4) {
    const float4 v = ((const float4*)in)[i];
    ushort4 o;
    o.x = f2bf(v.x); o.y = f2bf(v.y); o.z = f2bf(v.z); o.w = f2bf(v.w);
    ((ushort4*)out)[i] = o;
  }
}

// ---------------- LayerNorm fp32 -> bf16 (one row / block, D=1024) ----------------
__global__ __launch_bounds__(256) void k_ln(
    const float* __restrict__ x, const float* __restrict__ g,
    const float* __restrict__ bt, unsigned short* __restrict__ y) {
  const int row = blockIdx.x, t = threadIdx.x;
  const float4 v = ((const float4*)(x + (size_t)row * 1024))[t];
  float s1 = v.x + v.y + v.z + v.w;
  float s2 = v.x * v.x + v.y * v.y + v.z * v.z + v.w * v.w;
#pragma unroll
  for (int off = 1; off < 64; off <<= 1) {
    s1 += __shfl_xor(s1, off);
    s2 += __shfl_xor(s2, off);
  }
  __shared__ float r1[4], r2[4];
  if ((t & 63) == 0) { r1[t >> 6] = s1; r2[t >> 6] = s2; }
  __syncthreads();
  const float tot1 = r1[0] + r1[1] + r1[2] + r1[3];
  const float tot2 = r2[0] + r2[1] + r2[2] + r2[3];
  const float mean = tot1 * (1.0f / 1024.0f);
  const float var  = tot2 * (1.0f / 1024.0f) - mean * mean;
  const float rstd = rsqrtf(var + 1e-5f);
  const float4 gg = ((const float4*)g)[t];
  const float4 bb = ((const float4*)bt)[t];
  ushort4 o;
  o.x = f2bf((v.x - mean) * rstd * gg.x + bb.x);
  o.y = f2bf((v.y - mean) * rstd * gg.y + bb.y);
  o.z = f2bf((v.z - mean) * rstd * gg.z + bb.z);
  o.w = f2bf((v.w - mean) * rstd * gg.w + bb.w);
  ((ushort4*)(y + (size_t)row * 1024))[t] = o;
}

// ---------------- GEMM v2: C[M][N] = A[M][K](bf16) * Bt[N][K]^T(bf16) + bias ----------------
// BK=64: half the barriers of BK=32, 8-deep gload issue per stage.
// LDS rows are 128B -> XOR-swizzle both sides (source chunk ^ row&7, read addr ^ (row&7)<<4)
// to stay at 2-way bank aliasing (free). EPI 0: bf16. 1: +resid fp32. 2: GELU bf16.
// BN=128 or 64 (N=1024 GEMMs use 64 -> 2 blocks/CU). XCD chunked swizzle (nwg%8==0).
template <int EPI, int BN>
__global__ __launch_bounds__(256) void k_gemm(
    const unsigned short* __restrict__ A, const unsigned short* __restrict__ Bt,
    const float* __restrict__ bias, const float* __restrict__ resid,
    unsigned short* __restrict__ Obf, float* __restrict__ Of, int N, int K) {
  constexpr int NFR = BN / 32;                    // n-frags per wave: 4 or 2
  __shared__ __align__(16) unsigned short As[128 * 64];
  __shared__ __align__(16) unsigned short Bs[BN * 64];
  const int tid = threadIdx.x;
  const int wave = tid >> 6, lane = tid & 63;
  const int nwg = gridDim.x * gridDim.y;
  const int wg = blockIdx.y * gridDim.x + blockIdx.x;
  const int swz = (wg & 7) * (nwg >> 3) + (wg >> 3);   // chunked XCD swizzle
  const int bn = swz % gridDim.x, bm = swz / gridDim.x;
  const int la = lane & 15, g = lane >> 4;
  const int wr = wave >> 1, wc = wave & 1;
  f32x4 acc[4][NFR] = {};
  // staging: wave w, round r covers rows r*32 + w*8 .. +8 (1KB contiguous LDS).
  // lane l -> row +(l>>3), chunk l&7; source chunk pre-swizzled by row&7.
  const int rrow = lane >> 3;
  const int sc = ((lane & 7) ^ rrow) * 8;
  const unsigned short* ga = A  + (size_t)(bm * 128 + wave * 8 + rrow) * K + sc;
  const unsigned short* gb = Bt + (size_t)(bn * BN  + wave * 8 + rrow) * K + sc;
  for (int kt = 0; kt < K; kt += 64) {
#pragma unroll
    for (int r = 0; r < 4; ++r)
      gload_lds16(ga + (size_t)(r * 32) * K + kt, &As[(r * 32 + wave * 8) * 64]);
#pragma unroll
    for (int r = 0; r < BN / 32; ++r)
      gload_lds16(gb + (size_t)(r * 32) * K + kt, &Bs[(r * 32 + wave * 8) * 64]);
    __syncthreads();
#pragma unroll
    for (int kc = 0; kc < 2; ++kc) {
      bf16x8 af[4], bfr[NFR];
#pragma unroll
      for (int m = 0; m < 4; ++m) {
        const int row = wr * 64 + m * 16 + la;
        af[m] = *(const bf16x8*)((const char*)As + row * 128 +
                                 ((kc * 64 + g * 16) ^ ((row & 7) << 4)));
      }
#pragma unroll
      for (int n = 0; n < NFR; ++n) {
        const int row = wc * (BN / 2) + n * 16 + la;
        bfr[n] = *(const bf16x8*)((const char*)Bs + row * 128 +
                                  ((kc * 64 + g * 16) ^ ((row & 7) << 4)));
      }
#pragma unroll
      for (int m = 0; m < 4; ++m)
#pragma unroll
        for (int n = 0; n < NFR; ++n)
          acc[m][n] = __builtin_amdgcn_mfma_f32_16x16x32_bf16(af[m], bfr[n], acc[m][n], 0, 0, 0);
    }
    __syncthreads();
  }
#pragma unroll
  for (int m = 0; m < 4; ++m) {
    const int row = bm * 128 + wr * 64 + m * 16 + (lane >> 4) * 4;
#pragma unroll
    for (int n = 0; n < NFR; ++n) {
      const int col = bn * BN + wc * (BN / 2) + n * 16 + la;
      const float bv = bias[col];
#pragma unroll
      for (int r = 0; r < 4; ++r) {
        float v = acc[m][n][r] + bv;
        const size_t idx = (size_t)(row + r) * N + col;
        if constexpr (EPI == 0) {
          Obf[idx] = f2bf(v);
        } else if constexpr (EPI == 1) {
          Of[idx] = v + resid[idx];
        } else {
          v = 0.5f * v * (1.0f + erff(v * 0.70710678118654752f));
          Obf[idx] = f2bf(v);
        }
      }
    }
  }
}

// ---------------- flash attention v4 (proven 94us; v5 pipeline regressed) ----------------
// Swapped QK^T, per-lane softmax, raw s_barrier + counted vmcnt(4), scale
// pre-folded into Q weights (exp2 domain), cvt_pk bf16 pack, defer-rescale.
template <bool CAUSAL>
__global__ __launch_bounds__(256) void k_attn4(
    const unsigned short* __restrict__ Qb, int ldq, int qo0,
    const unsigned short* __restrict__ Kb, int ldk, int ko0,
    const unsigned short* __restrict__ Vtg,        // [b*H+h][64][TK]
    unsigned short* __restrict__ O, int TK) {
  __shared__ __align__(16) unsigned short Ks[2][64 * 64];
  __shared__ __align__(16) unsigned short Vs[2][64 * 64];
  __shared__ __align__(16) unsigned short Pl[4][16 * 64];
  const int qt = (blockIdx.x + blockIdx.y) & 31;   // balance causal work per CU
  const int h = blockIdx.y, b = blockIdx.z;
  const int bh = b * 16 + h;
  const int tid = threadIdx.x, wave = tid >> 6, lane = tid & 63;
  const int la = lane & 15, g = lane >> 4;
  const int qoff = qo0 + h * 64, koff = ko0 + h * 64;
  const size_t tok0 = (size_t)b * 2048;

  bf16x8 qf[2];                                    // Q as B-frag: col q=la, k=hd
  {
    const unsigned short* qp =
        Qb + (tok0 + qt * 64 + wave * 16 + la) * ldq + qoff + g * 8;
    qf[0] = *(const bf16x8*)qp;
    qf[1] = *(const bf16x8*)(qp + 32);
  }
  f32x4 oacc[4] = {};                              // O^T: col q=la, row d=g*4+r (+16*n4)
  float m_r = -1e30f, l_r = 0.0f;

  const int nkt = CAUSAL ? (qt + 1) : (TK >> 6);

  // staging: 64 rows x 128B per tile; wave w round r covers rows w*8+r*32..+8.
  const int rr = lane >> 3, cc = lane & 7;
  const int sc = (cc ^ rr) * 8;                    // pre-swizzled source chunk
  const unsigned short* Vrow = Vtg + (size_t)bh * 64 * TK;
  auto stage = [&](int kt, int buf) {
#pragma unroll
    for (int r = 0; r < 2; ++r) {
      const int row = wave * 8 + r * 32 + rr;
      gload_lds16(Kb + (tok0 + kt * 64 + row) * ldk + koff + sc,
                  &Ks[buf][(wave * 8 + r * 32) * 64]);
      gload_lds16(Vrow + (size_t)row * TK + kt * 64 + sc,
                  &Vs[buf][(wave * 8 + r * 32) * 64]);
    }
  };

  stage(0, 0);
  int cur = 0;
  char* pw = (char*)Pl[wave];
  const int lsw = (la & 7) << 4;

  for (int kt = 0; kt < nkt; ++kt) {
    if (kt + 1 < nkt) {
      stage(kt + 1, cur ^ 1);
      asm volatile("s_waitcnt vmcnt(4)" ::: "memory");   // this tile landed; 4 new in flight
    } else {
      asm volatile("s_waitcnt vmcnt(0)" ::: "memory");
    }
    __builtin_amdgcn_s_barrier();                  // raw: does NOT drain vmcnt

    // ---- S^T = K Q^T : lane -> (q=la, keys 16n+4g+r), already exp2-domain ----
    f32x4 s[4] = {};
    __builtin_amdgcn_s_setprio(1);
#pragma unroll
    for (int kc = 0; kc < 2; ++kc)
#pragma unroll
      for (int n = 0; n < 4; ++n) {
        const int key = n * 16 + la;
        const bf16x8 kfr = *(const bf16x8*)((const char*)&Ks[cur][0] +
            key * 128 + ((kc * 64 + g * 16) ^ ((key & 7) << 4)));
        s[n] = __builtin_amdgcn_mfma_f32_16x16x32_bf16(kfr, qf[kc], s[n], 0, 0, 0);
      }
    __builtin_amdgcn_s_setprio(0);

    // ---- per-lane online softmax (16 in-register values, defer-rescale) ----
    if (CAUSAL && kt == nkt - 1) {
      const int qloc = wave * 16 + la;
#pragma unroll
      for (int n = 0; n < 4; ++n)
#pragma unroll
        for (int r = 0; r < 4; ++r)
          if (n * 16 + g * 4 + r > qloc) s[n][r] = -1e30f;
    }
    float t0 = fmaxf(fmaxf(s[0][0], s[0][1]), fmaxf(s[0][2], s[0][3]));
    float t1 = fmaxf(fmaxf(s[1][0], s[1][1]), fmaxf(s[1][2], s[1][3]));
    float t2 = fmaxf(fmaxf(s[2][0], s[2][1]), fmaxf(s[2][2], s[2][3]));
    float t3 = fmaxf(fmaxf(s[3][0], s[3][1]), fmaxf(s[3][2], s[3][3]));
    float tm = fmaxf(fmaxf(t0, t1), fmaxf(t2, t3));
    tm = fmaxf(tm, __shfl_xor(tm, 16, 64));        // reduce across g (keeps la=q)
    tm = fmaxf(tm, __shfl_xor(tm, 32, 64));
    if (!__all(tm <= m_r + 8.0f)) {                // T13: rescale only on real growth
      const float mn = fmaxf(m_r, tm);
      const float al = exp2f(m_r - mn);
      m_r = mn;
      l_r *= al;
#pragma unroll
      for (int n4 = 0; n4 < 4; ++n4)
#pragma unroll
        for (int r = 0; r < 4; ++r) oacc[n4][r] *= al;
    }
    float p[4][4];
#pragma unroll
    for (int n = 0; n < 4; ++n)
#pragma unroll
      for (int r = 0; r < 4; ++r) p[n][r] = exp2f(s[n][r] - m_r);   // bounded by 2^8
    float rs = ((p[0][0] + p[0][1]) + (p[0][2] + p[0][3]))
             + ((p[1][0] + p[1][1]) + (p[1][2] + p[1][3]))
             + ((p[2][0] + p[2][1]) + (p[2][2] + p[2][3]))
             + ((p[3][0] + p[3][1]) + (p[3][2] + p[3][3]));
    rs += __shfl_xor(rs, 16, 64);
    rs += __shfl_xor(rs, 32, 64);
    l_r += rs;

    // ---- P^T -> per-wave LDS row q=la (cvt_pk u32 writes, swizzled) ----
#pragma unroll
    for (int n = 0; n < 4; ++n)
#pragma unroll
      for (int rp = 0; rp < 2; ++rp) {
        const unsigned int w = cvt_pk_bf16(p[n][2 * rp], p[n][2 * rp + 1]);
        *(unsigned int*)(pw + la * 128 + ((n * 32 + g * 8 + rp * 4) ^ lsw)) = w;
      }
    asm volatile("s_waitcnt lgkmcnt(0)" ::: "memory");
    bf16x8 pb[2];
    pb[0] = *(const bf16x8*)(pw + la * 128 + ((0 * 64 + g * 16) ^ lsw));
    pb[1] = *(const bf16x8*)(pw + la * 128 + ((1 * 64 + g * 16) ^ lsw));

    // ---- O^T += V^T P^T ----
    __builtin_amdgcn_s_setprio(1);
#pragma unroll
    for (int kc = 0; kc < 2; ++kc)
#pragma unroll
      for (int n4 = 0; n4 < 4; ++n4) {
        const int d = n4 * 16 + la;
        const bf16x8 vb = *(const bf16x8*)((const char*)&Vs[cur][0] +
            d * 128 + ((kc * 64 + g * 16) ^ ((d & 7) << 4)));
        oacc[n4] = __builtin_amdgcn_mfma_f32_16x16x32_bf16(vb, pb[kc], oacc[n4], 0, 0, 0);
      }
    __builtin_amdgcn_s_setprio(0);
    asm volatile("s_waitcnt lgkmcnt(0)" ::: "memory");
    __builtin_amdgcn_s_barrier();                  // all reads of buf done
    cur ^= 1;
  }

  // ---- epilogue: O^T -> LDS transpose -> coalesced O[q][d] stores ----
  const float inv = 1.0f / l_r;
#pragma unroll
  for (int n4 = 0; n4 < 4; ++n4)
#pragma unroll
    for (int rp = 0; rp < 2; ++rp) {
      const unsigned int w = cvt_pk_bf16(oacc[n4][2 * rp] * inv, oacc[n4][2 * rp + 1] * inv);
      *(unsigned int*)(pw + la * 128 + ((n4 * 32 + g * 8 + rp * 4) ^ lsw)) = w;
    }
  asm volatile("s_waitcnt lgkmcnt(0)" ::: "memory");
  const int q2 = lane >> 2, c4 = lane & 3;
  const size_t orow = tok0 + qt * 64 + wave * 16 + q2;
#pragma unroll
  for (int h8 = 0; h8 < 2; ++h8) {
    const bf16x8 v = *(const bf16x8*)(pw + q2 * 128 +
        ((c4 * 32 + h8 * 16) ^ ((q2 & 7) << 4)));
    *(bf16x8*)&O[orow * 1024 + h * 64 + c4 * 16 + h8 * 8] = v;
  }
}

// ---------------- workspace layout ----------------
constexpr size_t SZ_1K1K  = 1024ull * 1024 * 2;
constexpr size_t OFF_WQKV = 0;                         constexpr size_t SZ_WQKV = 3072ull * 1024 * 2;
constexpr size_t OFF_WPRJ = OFF_WQKV + SZ_WQKV;
constexpr size_t OFF_WQ   = OFF_WPRJ + SZ_1K1K;
constexpr size_t OFF_WKV  = OFF_WQ + SZ_1K1K;          constexpr size_t SZ_WKV = 2048ull * 1024 * 2;
constexpr size_t OFF_WCO  = OFF_WKV + SZ_WKV;
constexpr size_t OFF_WM1  = OFF_WCO + SZ_1K1K;         constexpr size_t SZ_WM1 = 4096ull * 1024 * 2;
constexpr size_t OFF_WM2  = OFF_WM1 + SZ_WM1;          constexpr size_t SZ_WM2 = 1024ull * 4096 * 2;
constexpr size_t OFF_ENCB = OFF_WM2 + SZ_WM2;          constexpr size_t SZ_ACT = 4096ull * 1024 * 2;
constexpr size_t OFF_XCUR = OFF_ENCB + SZ_ACT;         constexpr size_t SZ_XF  = 4096ull * 1024 * 4;
constexpr size_t OFF_LNO  = OFF_XCUR + SZ_XF;
constexpr size_t OFF_BIG  = OFF_LNO + SZ_ACT;          constexpr size_t SZ_BIG = 4096ull * 4096 * 2;
constexpr size_t OFF_ATTN = OFF_BIG + SZ_BIG;
constexpr size_t OFF_QPRJ = OFF_ATTN + SZ_ACT;
constexpr size_t OFF_BQKV = OFF_QPRJ + SZ_ACT;         // scaled qkv bias (3072 f32)
constexpr size_t OFF_BQ   = OFF_BQKV + 3072 * 4;       // scaled q bias (1024 f32)
constexpr size_t WS_NEED  = OFF_BQ + 1024 * 4;

extern "C" void kernel_launch(void* const* d_in, const int* in_sizes, int n_in,
                              void* d_out, int out_size, void* d_ws, size_t ws_size,
                              hipStream_t stream) {
  (void)in_sizes; (void)n_in; (void)out_size;
  if (ws_size < WS_NEED) return;  // workspace too small -> visible as absmax fail

  const float* x     = (const float*)d_in[0];
  const float* enc   = (const float*)d_in[1];
  const float* ln1g  = (const float*)d_in[3];
  const float* ln1b  = (const float*)d_in[4];
  const float* ln2g  = (const float*)d_in[5];
  const float* ln2b  = (const float*)d_in[6];
  const float* ln3g  = (const float*)d_in[7];
  const float* ln3b  = (const float*)d_in[8];
  const float* qkv_w = (const float*)d_in[9];
  const float* qkv_b = (const float*)d_in[10];
  const float* prj_w = (const float*)d_in[11];
  const float* prj_b = (const float*)d_in[12];
  const float* q_w   = (const float*)d_in[13];
  const float* q_b   = (const float*)d_in[14];
  const float* kv_w  = (const float*)d_in[15];
  const float* kv_b  = (const float*)d_in[16];
  const float* co_w  = (const float*)d_in[17];
  const float* co_b  = (const float*)d_in[18];
  const float* m1_w  = (const float*)d_in[19];
  const float* m1_b  = (const float*)d_in[20];
  const float* m2_w  = (const float*)d_in[21];
  const float* m2_b  = (const float*)d_in[22];
  float* out = (float*)d_out;

  char* ws = (char*)d_ws;
  unsigned short* wqkv = (unsigned short*)(ws + OFF_WQKV);
  unsigned short* wprj = (unsigned short*)(ws + OFF_WPRJ);
  unsigned short* wq   = (unsigned short*)(ws + OFF_WQ);
  unsigned short* wkv  = (unsigned short*)(ws + OFF_WKV);
  unsigned short* wco  = (unsigned short*)(ws + OFF_WCO);
  unsigned short* wm1  = (unsigned short*)(ws + OFF_WM1);
  unsigned short* wm2  = (unsigned short*)(ws + OFF_WM2);
  unsigned short* encb = (unsigned short*)(ws + OFF_ENCB);
  float*          xcur = (float*)(ws + OFF_XCUR);
  unsigned short* lno  = (unsigned short*)(ws + OFF_LNO);
  unsigned short* big  = (unsigned short*)(ws + OFF_BIG);
  unsigned short* attnb= (unsigned short*)(ws + OFF_ATTN);
  unsigned short* qprj = (unsigned short*)(ws + OFF_QPRJ);
  float*          bqkv = (float*)(ws + OFF_BQKV);
  float*          bq   = (float*)(ws + OFF_BQ);
  // V^T scratch lives in the unused tail of `big`:
  unsigned short* vtS  = big + (size_t)4096 * 3072;
  unsigned short* vtC  = big + (size_t)4096 * 2048;

  const dim3 tb(32, 8);
  // weights -> bf16 transposed [N][K]; Q-producing columns pre-scaled by QSCALE
  k_transpose_bf16<<<dim3(3072/32, 1024/32), tb, 0, stream>>>(qkv_w, wqkv, 1024, 3072, 0, 1024, QSCALE);
  k_transpose_bf16<<<dim3(1024/32, 1024/32), tb, 0, stream>>>(prj_w, wprj, 1024, 1024, 0, 0, 1.0f);
  k_transpose_bf16<<<dim3(1024/32, 1024/32), tb, 0, stream>>>(q_w,   wq,   1024, 1024, 0, 1024, QSCALE);
  k_transpose_bf16<<<dim3(2048/32, 1024/32), tb, 0, stream>>>(kv_w,  wkv,  1024, 2048, 0, 0, 1.0f);
  k_transpose_bf16<<<dim3(1024/32, 1024/32), tb, 0, stream>>>(co_w,  wco,  1024, 1024, 0, 0, 1.0f);
  k_transpose_bf16<<<dim3(4096/32, 1024/32), tb, 0, stream>>>(m1_w,  wm1,  1024, 4096, 0, 0, 1.0f);
  k_transpose_bf16<<<dim3(1024/32, 4096/32), tb, 0, stream>>>(m2_w,  wm2,  4096, 1024, 0, 0, 1.0f);
  k_scale_bias<<<12, 256, 0, stream>>>(qkv_b, bqkv, 3072, 0, 1024, QSCALE);
  k_scale_bias<<<4, 256, 0, stream>>>(q_b, bq, 1024, 0, 1024, QSCALE);
  k_f32_to_bf16<<<4096, 256, 0, stream>>>(enc, encb, 1048576);

  // ---- self-attention block ----
  k_ln<<<4096, 256, 0, stream>>>(x, ln1g, ln1b, lno);
  k_gemm<0,128><<<dim3(24, 32), 256, 0, stream>>>(lno, wqkv, bqkv, nullptr, big, nullptr, 3072, 1024);
  k_vtrans<<<dim3(64, 2, 32), tb, 0, stream>>>(big, 3072, 2048, vtS, 2048);
  k_attn4<true><<<dim3(32, 16, 2), 256, 0, stream>>>(big, 3072, 0,
                                                     big, 3072, 1024,
                                                     vtS, attnb, 2048);
  k_gemm<1,64><<<dim3(16, 32), 256, 0, stream>>>(attnb, wprj, prj_b, x, nullptr, xcur, 1024, 1024);

  // ---- cross-attention block ----
  k_ln<<<4096, 256, 0, stream>>>(xcur, ln2g, ln2b, lno);
  k_gemm<0,64><<<dim3(16, 32), 256, 0, stream>>>(lno,  wq,  bq,   nullptr, qprj, nullptr, 1024, 1024);
  k_gemm<0,128><<<dim3(16, 32), 256, 0, stream>>>(encb, wkv, kv_b, nullptr, big,  nullptr, 2048, 1024);
  k_vtrans<<<dim3(64, 2, 32), tb, 0, stream>>>(big, 2048, 1024, vtC, 2048);
  k_attn4<false><<<dim3(32, 16, 2), 256, 0, stream>>>(qprj, 1024, 0,
                                                      big,  2048, 0,
                                                      vtC, attnb, 2048);
  k_gemm<1,64><<<dim3(16, 32), 256, 0, stream>>>(attnb, wco, co_b, xcur, nullptr, xcur, 1024, 1024);

  // ---- MLP block ----
  k_ln<<<4096, 256, 0, stream>>>(xcur, ln3g, ln3b, lno);
  k_gemm<2,128><<<dim3(32, 32), 256, 0, stream>>>(lno, wm1, m1_b, nullptr, big, nullptr, 4096, 1024);
  k_gemm<1,64><<<dim3(16, 32), 256, 0, stream>>>(big, wm2, m2_b, xcur, nullptr, out, 1024, 4096);
}